// Round 6
// baseline (171.162 us; speedup 1.0000x reference)
//
#include <hip/hip_runtime.h>
#include <hip/hip_bf16.h>
#include <stdint.h>

// ---------------------------------------------------------------------------
// TensorNet: fused encoder MLP (128->256->256->256, relu) over 32x4096 tokens,
// per-batch mean -> p = relu(m^2) -> decoder MLP (256->512->512->10).
//
// R21: FP8 h-tiles. Occupancy data across R12/R16/R17/R20 fits
// blocks/CU ~= floor(64KB / LDS) (effective LDS occupancy pool ~64KB, not
// 160KB). bf16 h-tile (64x256x2B=32KB) pins us at 2 blocks/CU. This round:
// h1/h2 and W2/W3 in OCP e4m3 via mfma_f32_16x16x32_fp8_fp8 (same K=32 and
// same rate as bf16) -> LDS 16384B at MTILE=64, NBLK unchanged 2048 ->
// 4 blocks/CU (or 8 if the pool is really 160KB). Also: epilogue rewritten
// as register shfl_xor butterfly + direct atomics (old 17KB scratch no
// longer fits; removes 2 barriers -> 5 total). Layer 1 stays bf16.
//
// HARD RULES from the log:
//  - NEVER pass a min-waves arg to __launch_bounds__ (R5, R19: spills).
//  - NEVER grow per-wave a-load count / VGPR for "sharing" (R18: 185us).
//  - NEVER shrink MTILE (R20: +34% blocks, zero residency gain).
//  - Residency at constant block count is the lever (R17: -17%).
//
// Explored & rejected: MTILE=128 (R16), MTILE=48 (R20), wave->token remap
// (R18), direct-global B-frags (R5/R6), manual ping-pong (R13), cooperative
// single-kernel (R11), decoder-in-encoder tail (R14/R15).
// ---------------------------------------------------------------------------

#define NIN   128
#define NHID  256
#define NDEC  512
#define NOUTC 10
#define BATCH 32
#define NTOK  4096
#define MTILE 64
#define NBLK  (BATCH * (NTOK / MTILE))   // 2048 encoder tiles

#define SWZ(t) (((t) & 7) << 4)          // XOR swizzle, byte bits 4-6

typedef short bf16x8 __attribute__((ext_vector_type(8)));
typedef float floatx4 __attribute__((ext_vector_type(4)));

__device__ __forceinline__ uint16_t f2b(float f) {
  union { uint32_t u; float f; } v; v.f = f;
  uint32_t r = v.u + 0x7FFFu + ((v.u >> 16) & 1u);   // RNE
  return (uint16_t)(r >> 16);
}
__device__ __forceinline__ uint32_t pkbf(float lo, float hi) {
  __hip_bfloat162 h = __float22bfloat162_rn(float2{lo, hi});  // v_cvt_pk_bf16_f32
  union { __hip_bfloat162 h; uint32_t u; } c; c.h = h;
  return c.u;
}

// ---------------------------------------------------------------------------
// Pack weights into MFMA-A-fragment order: W1 -> bf16 (bytes [0,64K)),
// W2/W3 -> fp8 e4m3 (bytes [64K,128K) / [128K,192K)). All three use the
// same lane mapping (k = kc*32 + (ln>>4)*8 + j, m = mt*16 + (ln&15)); the
// flat destination index equals p within each region. Also zero-inits msum
// and pre-loads out with c3 (decoder atomics accumulate on top).
// ---------------------------------------------------------------------------
__global__ __launch_bounds__(256) void pack_weights(
    const float* __restrict__ W1, const float* __restrict__ W2,
    const float* __restrict__ W3, const float* __restrict__ c3,
    uint8_t* __restrict__ pW, float* __restrict__ msum,
    float* __restrict__ out) {
  int p = blockIdx.x * blockDim.x + threadIdx.x;
  if (p < BATCH * NHID) msum[p] = 0.f;
  if (p < BATCH * NOUTC) out[p] = c3[p % NOUTC];
  if (p < 32768) {
    // W1: K=128, KC=4, bf16
    int j = p & 7, ln = (p >> 3) & 63, rest = p >> 9;
    int kc = rest & 3, mt = rest >> 2;
    int m = mt * 16 + (ln & 15);
    int k = kc * 32 + ((ln >> 4) << 3) + j;
    ((uint16_t*)pW)[p] = f2b(W1[k * NHID + m]);
  } else {
    int p2 = p - 32768;
    const float* W = (p2 < 65536) ? W2 : W3;
    int base = (p2 < 65536) ? 65536 : 131072;
    if (p2 >= 65536) p2 -= 65536;
    // K=256, KC=8, fp8 e4m3
    int j = p2 & 7, ln = (p2 >> 3) & 63, rest = p2 >> 9;
    int kc = rest & 7, mt = rest >> 3;
    int m = mt * 16 + (ln & 15);
    int k = kc * 32 + ((ln >> 4) << 3) + j;
    int r = __builtin_amdgcn_cvt_pk_fp8_f32(W[k * NHID + m], 0.f, 0, false);
    pW[base + p2] = (uint8_t)(r & 0xFF);
  }
}

// ---------------------------------------------------------------------------
// Fused encoder. Block = 256 thr (4 waves), 64 tokens. Wave w owns hidden
// rows [64w,64w+64). LDS = 16384 B: x-tile (64x256B bf16) overlaid with
// fp8 h-tiles (64x256B). 5 barriers. Epilogue: shfl_xor token-sum butterfly
// (no scratch), 4 lanes/wave issue direct atomicAdds.
// ---------------------------------------------------------------------------
__global__ __launch_bounds__(256) void encoder(
    const float* __restrict__ x,        // [BATCH*NTOK][NIN] fp32
    const uint8_t* __restrict__ pW,
    const float* __restrict__ b1,
    const float* __restrict__ b2,
    const float* __restrict__ b3,
    float* __restrict__ msum) {         // [BATCH][NHID] fp32 accum
  __shared__ __align__(16) uint8_t Hs[MTILE * 256];   // 16384 B

  const int tid  = threadIdx.x;
  const int wave = tid >> 6;
  const int lane = tid & 63;
  const int l15  = lane & 15;
  const int q    = lane >> 4;
  const int tok0  = blockIdx.x * MTILE;
  const int batch = blockIdx.x >> 6;          // 64 tiles per batch

  const uint16_t* pW1 = (const uint16_t*)pW;  // bf16 frags, KC=4
  const uint8_t*  pW2 = pW + 65536;           // fp8 frags, KC=8
  const uint8_t*  pW3 = pW + 131072;          // fp8 frags, KC=8

  // ---- stage x tile: 64 tokens x 128 ch fp32 -> bf16, row stride 256B ----
  {
    const float4* xv = (const float4*)(x + (size_t)tok0 * NIN);
#pragma unroll
    for (int i = 0; i < 4; ++i) {
      const int u = tid + i * 256;            // 8-float unit, 0..1023
      float4 va = xv[2 * u];
      float4 vb = xv[2 * u + 1];
      uint4 w = make_uint4(pkbf(va.x, va.y), pkbf(va.z, va.w),
                           pkbf(vb.x, vb.y), pkbf(vb.z, vb.w));
      const int row = u >> 4;                 // token 0..63
      const int cb  = (u & 15) << 4;          // byte col 0..240
      *(uint4*)&Hs[row * 256 + (cb ^ SWZ(row))] = w;
    }
  }
  __syncthreads();

  floatx4 acc[4][4];   // [jt][tt]

  // ---- layer 1: K = 128 bf16, A = W1^T, B = x; acc init = bias ----
#pragma unroll
  for (int jt = 0; jt < 4; ++jt) {
    const float4 bb = *(const float4*)&b1[wave * 64 + jt * 16 + q * 4];
#pragma unroll
    for (int tt = 0; tt < 4; ++tt)
      acc[jt][tt] = (floatx4){bb.x, bb.y, bb.z, bb.w};
  }
#pragma unroll
  for (int kc = 0; kc < 4; ++kc) {
    bf16x8 a[4], b[4];
#pragma unroll
    for (int jt = 0; jt < 4; ++jt)
      a[jt] = *(const bf16x8*)(pW1 + ((((wave * 4 + jt) * 4 + kc) * 64 + lane) << 3));
#pragma unroll
    for (int tt = 0; tt < 4; ++tt) {
      const int t = tt * 16 + l15;
      b[tt] = *(const bf16x8*)&Hs[t * 256 + ((kc * 64 + q * 16) ^ SWZ(t))];
    }
#pragma unroll
    for (int jt = 0; jt < 4; ++jt)
#pragma unroll
      for (int tt = 0; tt < 4; ++tt)
        acc[jt][tt] = __builtin_amdgcn_mfma_f32_16x16x32_bf16(
            a[jt], b[tt], acc[jt][tt], 0, 0, 0);
  }
  __syncthreads();   // x reads done before h1 overwrites

  // ---- h1 = relu(acc) -> fp8, row stride 256B (overwrites x region) ----
#pragma unroll
  for (int jt = 0; jt < 4; ++jt) {
    const int j0 = wave * 64 + jt * 16 + q * 4;   // byte col == hidden idx
#pragma unroll
    for (int tt = 0; tt < 4; ++tt) {
      const int t = tt * 16 + l15;
      float v0 = fmaxf(acc[jt][tt][0], 0.f);
      float v1 = fmaxf(acc[jt][tt][1], 0.f);
      float v2 = fmaxf(acc[jt][tt][2], 0.f);
      float v3 = fmaxf(acc[jt][tt][3], 0.f);
      int u = __builtin_amdgcn_cvt_pk_fp8_f32(v0, v1, 0, false);
      u = __builtin_amdgcn_cvt_pk_fp8_f32(v2, v3, u, true);
      *(uint32_t*)&Hs[t * 256 + (j0 ^ SWZ(t))] = (uint32_t)u;
    }
  }
  __syncthreads();

  // ---- layer 2: K = 256 fp8, A = W2^T, B = h1 ----
#pragma unroll
  for (int jt = 0; jt < 4; ++jt) {
    const float4 bb = *(const float4*)&b2[wave * 64 + jt * 16 + q * 4];
#pragma unroll
    for (int tt = 0; tt < 4; ++tt)
      acc[jt][tt] = (floatx4){bb.x, bb.y, bb.z, bb.w};
  }
#pragma unroll
  for (int kc = 0; kc < 8; ++kc) {
    long a[4], b[4];
#pragma unroll
    for (int jt = 0; jt < 4; ++jt)
      a[jt] = *(const long*)(pW2 + ((((wave * 4 + jt) * 8 + kc) * 64 + lane) << 3));
#pragma unroll
    for (int tt = 0; tt < 4; ++tt) {
      const int t = tt * 16 + l15;
      b[tt] = *(const long*)&Hs[t * 256 + ((kc * 32 + q * 8) ^ SWZ(t))];
    }
#pragma unroll
    for (int jt = 0; jt < 4; ++jt)
#pragma unroll
      for (int tt = 0; tt < 4; ++tt)
        acc[jt][tt] = __builtin_amdgcn_mfma_f32_16x16x32_fp8_fp8(
            a[jt], b[tt], acc[jt][tt], 0, 0, 0);
  }
  __syncthreads();   // h1 reads done before h2 overwrites

  // ---- h2 = relu(acc) -> fp8 ----
#pragma unroll
  for (int jt = 0; jt < 4; ++jt) {
    const int j0 = wave * 64 + jt * 16 + q * 4;
#pragma unroll
    for (int tt = 0; tt < 4; ++tt) {
      const int t = tt * 16 + l15;
      float v0 = fmaxf(acc[jt][tt][0], 0.f);
      float v1 = fmaxf(acc[jt][tt][1], 0.f);
      float v2 = fmaxf(acc[jt][tt][2], 0.f);
      float v3 = fmaxf(acc[jt][tt][3], 0.f);
      int u = __builtin_amdgcn_cvt_pk_fp8_f32(v0, v1, 0, false);
      u = __builtin_amdgcn_cvt_pk_fp8_f32(v2, v3, u, true);
      *(uint32_t*)&Hs[t * 256 + (j0 ^ SWZ(t))] = (uint32_t)u;
    }
  }
  __syncthreads();

  // ---- layer 3: K = 256 fp8, A = W3^T, B = h2, fused token-sum ----
#pragma unroll
  for (int jt = 0; jt < 4; ++jt) {
    const float4 bb = *(const float4*)&b3[wave * 64 + jt * 16 + q * 4];
#pragma unroll
    for (int tt = 0; tt < 4; ++tt)
      acc[jt][tt] = (floatx4){bb.x, bb.y, bb.z, bb.w};
  }
#pragma unroll
  for (int kc = 0; kc < 8; ++kc) {
    long a[4], b[4];
#pragma unroll
    for (int jt = 0; jt < 4; ++jt)
      a[jt] = *(const long*)(pW3 + ((((wave * 4 + jt) * 8 + kc) * 64 + lane) << 3));
#pragma unroll
    for (int tt = 0; tt < 4; ++tt) {
      const int t = tt * 16 + l15;
      b[tt] = *(const long*)&Hs[t * 256 + ((kc * 32 + q * 8) ^ SWZ(t))];
    }
#pragma unroll
    for (int jt = 0; jt < 4; ++jt)
#pragma unroll
      for (int tt = 0; tt < 4; ++tt)
        acc[jt][tt] = __builtin_amdgcn_mfma_f32_16x16x32_fp8_fp8(
            a[jt], b[tt], acc[jt][tt], 0, 0, 0);
  }
  // No further LDS use: relu + token-sum entirely in registers.
  // Sum over 64 tokens = sum over tt (serial) then over l15 (shfl butterfly;
  // masks 1,2,4,8 stay within each 16-lane group; q indexes output rows).
#pragma unroll
  for (int jt = 0; jt < 4; ++jt) {
    float s0 = 0.f, s1 = 0.f, s2 = 0.f, s3 = 0.f;
#pragma unroll
    for (int tt = 0; tt < 4; ++tt) {
      s0 += fmaxf(acc[jt][tt][0], 0.f);
      s1 += fmaxf(acc[jt][tt][1], 0.f);
      s2 += fmaxf(acc[jt][tt][2], 0.f);
      s3 += fmaxf(acc[jt][tt][3], 0.f);
    }
#pragma unroll
    for (int m = 1; m <= 8; m <<= 1) {
      s0 += __shfl_xor(s0, m);
      s1 += __shfl_xor(s1, m);
      s2 += __shfl_xor(s2, m);
      s3 += __shfl_xor(s3, m);
    }
    if (l15 == 0) {
      const int jb = batch * NHID + wave * 64 + jt * 16 + q * 4;
      atomicAdd(&msum[jb + 0], s0);
      atomicAdd(&msum[jb + 1], s1);
      atomicAdd(&msum[jb + 2], s2);
      atomicAdd(&msum[jb + 3], s3);
    }
  }
}

// ---------------------------------------------------------------------------
// Decoder: 128 blocks = (batch x d2-quarter), 1024 threads. Each block
// computes the full d1 (redundant x4, D1 is L2-resident), its 128-wide d2
// quarter, and atomicAdds its partial L3 dot into out (pre-init'd to c3).
// ---------------------------------------------------------------------------
__global__ __launch_bounds__(1024) void decoder(
    const float* __restrict__ msum,
    const float* __restrict__ D1, const float* __restrict__ c1,
    const float* __restrict__ D2, const float* __restrict__ c2,
    const float* __restrict__ D3,
    float* __restrict__ out) {
  __shared__ float p[NHID];
  __shared__ float d1[NDEC];
  __shared__ float d2q[128];
  __shared__ __align__(16) float red[4096];   // 16 KB
  const int b = blockIdx.x >> 2, qd = blockIdx.x & 3, t = threadIdx.x;

  if (t < NHID) {
    float m = msum[b * NHID + t] * (1.f / NTOK);
    p[t] = m * m;                        // relu(m^2) == m^2
  }
  __syncthreads();

  // ---- layer 1 (full, redundant x4): K = 256 -> 32 k per split ----
  {
    const int jg = t & 127;              // j-group of 4
    const int ks = t >> 7;               // 0..7 K-split
    const float4* D1v = (const float4*)D1;   // [256][128] float4
    float4 s = {0.f, 0.f, 0.f, 0.f};
    for (int k = ks * 32; k < ks * 32 + 32; ++k) {
      float4 w = D1v[k * 128 + jg];
      float pv = p[k];
      s.x += pv * w.x; s.y += pv * w.y; s.z += pv * w.z; s.w += pv * w.w;
    }
    *(float4*)&red[t * 4] = s;
    __syncthreads();
    if (t < NDEC) {
      float v = c1[t];
#pragma unroll
      for (int i = 0; i < 8; ++i) v += red[i * 512 + t];
      d1[t] = fmaxf(v, 0.f);
    }
    __syncthreads();
  }

  // ---- layer 2 (quarter): 128 outs, K = 512 -> 32 splits x 16 k ----
  {
    const int jg2 = t & 31;              // float4 group within quarter
    const int ks2 = t >> 5;              // 0..31 K-split
    const float4* D2v = (const float4*)D2;   // [512][128] float4
    float4 s = {0.f, 0.f, 0.f, 0.f};
    for (int k = ks2 * 16; k < ks2 * 16 + 16; ++k) {
      float4 w = D2v[k * 128 + qd * 32 + jg2];
      float hv = d1[k];
      s.x += hv * w.x; s.y += hv * w.y; s.z += hv * w.z; s.w += hv * w.w;
    }
    *(float4*)&red[t * 4] = s;           // == red[ks2*128 + jg2*4 + c]
    __syncthreads();
    if (t < 128) {
      float v = c2[qd * 128 + t];
#pragma unroll
      for (int i = 0; i < 32; ++i) v += red[i * 128 + t];
      d2q[t] = fmaxf(v, 0.f);
    }
    __syncthreads();
  }

  // ---- layer 3 partial: quarter K = 128; 64 k-chunks x 16 j-slots ----
  {
    const int j3 = t & 15;
    const int kc = t >> 4;               // 0..63, 2 k's each
    float s = 0.f;
    if (j3 < NOUTC)
      for (int k = kc * 2; k < kc * 2 + 2; ++k)
        s += d2q[k] * D3[(qd * 128 + k) * NOUTC + j3];
    red[t] = s;
    __syncthreads();
    if (t < NOUTC) {
      float v = 0.f;
#pragma unroll
      for (int i = 0; i < 64; ++i) v += red[i * 16 + t];
      atomicAdd(&out[b * NOUTC + t], v);
    }
  }
}

// ---------------------------------------------------------------------------
extern "C" void kernel_launch(void* const* d_in, const int* in_sizes, int n_in,
                              void* d_out, int out_size, void* d_ws, size_t ws_size,
                              hipStream_t stream) {
  const float* x  = (const float*)d_in[0];
  const float* W1 = (const float*)d_in[1];
  const float* b1 = (const float*)d_in[2];
  const float* W2 = (const float*)d_in[3];
  const float* b2 = (const float*)d_in[4];
  const float* W3 = (const float*)d_in[5];
  const float* b3 = (const float*)d_in[6];
  const float* D1 = (const float*)d_in[7];
  const float* c1 = (const float*)d_in[8];
  const float* D2 = (const float*)d_in[9];
  const float* c2 = (const float*)d_in[10];
  const float* D3 = (const float*)d_in[11];
  const float* c3 = (const float*)d_in[12];

  // ws: [0,64K) bf16 W1 | [64K,128K) fp8 W2 | [128K,192K) fp8 W3 |
  //     [384K,416K) msum
  uint8_t* pW   = (uint8_t*)d_ws;
  float*   msum = (float*)((char*)d_ws + 384 * 1024);

  pack_weights<<<640, 256, 0, stream>>>(W1, W2, W3, c3, pW, msum,
                                        (float*)d_out);
  encoder<<<NBLK, 256, 0, stream>>>(x, pW, b1, b2, b3, msum);
  decoder<<<128, 1024, 0, stream>>>(msum, D1, c1, D2, c2, D3,
                                    (float*)d_out);
}